// Round 7
// baseline (139.431 us; speedup 1.0000x reference)
//
#include <hip/hip_runtime.h>

// Problem constants (fixed by setup_inputs in the reference).
#define BB 128
#define CC 3
#define HH 224
#define WW 224
#define PP 16

#define W4 (WW / 4)               // 56 float4 per row
#define CHAN4 (HH * W4)           // 12544 float4 per channel
#define PER_IMG4 (CC * CHAN4)     // 37632 float4 per image

#define ROWS_PER_BLK 32           // 32 rows * 56 = 1792 = 7 * 256 (exact, row-aligned)
#define POS_PER_BLK (ROWS_PER_BLK * W4)
#define ITERS (POS_PER_BLK / 256) // 7
#define BLKS_PER_IMG (HH / ROWS_PER_BLK)  // 7
#define NBLK (BB * BLKS_PER_IMG)  // 896 blocks -> 3.5 blocks/CU, all co-resident
#define NW (ROWS_PER_BLK * 7)     // 224 mask words (32 rows x 7 words)

typedef float vfloat4 __attribute__((ext_vector_type(4)));

// ---------------------------------------------------------------------------
// Each block owns a 32-row x 224-col window of ONE image (channel-invariant
// mask), builds the window's bitmask once in LDS (~21 intersecting patches),
// then streams 7 iterations x 3 channels of float4s. Mask build amortized
// 21x vs one-256-chunk-per-block; fully-masked float4s skip the global load.
// ---------------------------------------------------------------------------
__global__ __launch_bounds__(256) void occl_fused(
        vfloat4* __restrict__ out, const vfloat4* __restrict__ imgs,
        const int* __restrict__ px, const int* __restrict__ py, int N) {
    const int t  = threadIdx.x;
    const int b  = blockIdx.x / BLKS_PER_IMG;         // image index
    const int h0 = (blockIdx.x % BLKS_PER_IMG) * ROWS_PER_BLK;

    __shared__ unsigned int rowbits[NW];
    if (t < NW) rowbits[t] = 0u;
    __syncthreads();

    // Build: one patch per thread (N=98 < 256), rows clipped to [h0, h0+32).
    if (t < N) {
        int x = px[b * N + t];
        int y = py[b * N + t];
        int lo = x > h0 ? x : h0;
        int hi = (x + PP < h0 + ROWS_PER_BLK) ? (x + PP) : (h0 + ROWS_PER_BLK);
        if (lo < hi) {
            unsigned long long mm = 0xFFFFull << (y & 31);
            unsigned int lo32 = (unsigned int)mm;
            unsigned int hi32 = (unsigned int)(mm >> 32);
            int woff = y >> 5;
            for (int h = lo; h < hi; ++h) {
                int base = (h - h0) * 7 + woff;
                atomicOr(&rowbits[base], lo32);
                if (hi32) atomicOr(&rowbits[base + 1], hi32);
            }
        }
    }
    __syncthreads();

    // Stream: 7 iterations x 3 channels over the block's 1792 positions.
    const size_t imgBase = (size_t)b * PER_IMG4;
    const int p0 = h0 * W4;
    for (int k = 0; k < ITERS; ++k) {
        int p  = p0 + k * 256 + t;        // position within channel
        int w4 = p % W4;
        int h  = p / W4;
        unsigned int word = rowbits[(h - h0) * 7 + (w4 >> 3)];
        unsigned int m4 = (word >> ((w4 & 7) * 4)) & 0xFu;

        size_t f0 = imgBase + p;
        vfloat4 z = {0.f, 0.f, 0.f, 0.f};
        vfloat4 v0 = z, v1 = z, v2 = z;
        if (m4 != 0xFu) {                 // all-masked: skip the loads
            v0 = __builtin_nontemporal_load(&imgs[f0]);
            v1 = __builtin_nontemporal_load(&imgs[f0 + CHAN4]);
            v2 = __builtin_nontemporal_load(&imgs[f0 + 2 * CHAN4]);
            if (m4 & 1u) { v0.x = 0.f; v1.x = 0.f; v2.x = 0.f; }
            if (m4 & 2u) { v0.y = 0.f; v1.y = 0.f; v2.y = 0.f; }
            if (m4 & 4u) { v0.z = 0.f; v1.z = 0.f; v2.z = 0.f; }
            if (m4 & 8u) { v0.w = 0.f; v1.w = 0.f; v2.w = 0.f; }
        }
        __builtin_nontemporal_store(v0, &out[f0]);
        __builtin_nontemporal_store(v1, &out[f0 + CHAN4]);
        __builtin_nontemporal_store(v2, &out[f0 + 2 * CHAN4]);
    }
}

extern "C" void kernel_launch(void* const* d_in, const int* in_sizes, int n_in,
                              void* d_out, int out_size, void* d_ws, size_t ws_size,
                              hipStream_t stream) {
    const float* imgs = (const float*)d_in[0];
    const int*   px   = (const int*)d_in[1];
    const int*   py   = (const int*)d_in[2];
    float*       out  = (float*)d_out;

    const int N = in_sizes[1] / BB;  // points per image (98)

    occl_fused<<<NBLK, 256, 0, stream>>>(
        (vfloat4*)out, (const vfloat4*)imgs, px, py, N);
}

// Round 8
// 135.474 us; speedup vs baseline: 1.0292x; 1.0292x over previous
//
#include <hip/hip_runtime.h>

// Problem constants (fixed by setup_inputs in the reference).
#define BB 128
#define CC 3
#define HH 224
#define WW 224
#define PP 16

#define W4 (WW / 4)               // 56 float4 per row
#define CHAN4 (HH * W4)           // 12544 float4 per channel = 49 * 256 (exact)
#define PER_IMG4 (CC * CHAN4)     // 37632 float4 per image
#define NROWS 6                   // 256 (h,w4) positions span at most 6 rows
#define NBLK (BB * (CHAN4 / 256)) // 128 * 49 = 6272 blocks (~24.5/CU)

typedef float vfloat4 __attribute__((ext_vector_type(4)));

// ---------------------------------------------------------------------------
// Measured-best structure (R6): each block owns 256 (h,w4) positions of ONE
// image (mask is channel-invariant), builds a 6-row LDS bitmask from the
// point list, then streams all 3 channels at those positions. Heavy
// oversubscription (24.5 blocks/CU) hides the lockstep build phase — the
// 896-block variant (R7) lost 4.8us to CU load imbalance. Point loads are
// hoisted above the first barrier so VMEM latency overlaps it.
// ---------------------------------------------------------------------------
__global__ __launch_bounds__(256) void occl_fused(
        vfloat4* __restrict__ out, const vfloat4* __restrict__ imgs,
        const int* __restrict__ px, const int* __restrict__ py, int N) {
    const int t     = threadIdx.x;
    const int b     = blockIdx.x / (CHAN4 / 256);    // image index
    const int posF0 = (blockIdx.x % (CHAN4 / 256)) * 256;
    const int h0    = posF0 / W4;                    // first row in window

    // Issue point loads before the barrier; latency overlaps LDS zero + sync.
    int x = 0, y = 0;
    if (t < N) {
        x = px[b * N + t];
        y = py[b * N + t];
    }

    __shared__ unsigned int rowbits[NROWS * 7];      // 6 rows x 7 mask words
    if (t < NROWS * 7) rowbits[t] = 0u;
    __syncthreads();

    // Build: one patch per thread (N=98 < 256), rows clipped to [h0, h0+6).
    if (t < N) {
        int lo = x > h0 ? x : h0;
        int hi = (x + PP < h0 + NROWS) ? (x + PP) : (h0 + NROWS);
        if (lo < hi) {
            unsigned long long mm = 0xFFFFull << (y & 31);
            unsigned int lo32 = (unsigned int)mm;
            unsigned int hi32 = (unsigned int)(mm >> 32);
            int woff = y >> 5;
            for (int h = lo; h < hi; ++h) {
                int base = (h - h0) * 7 + woff;
                atomicOr(&rowbits[base], lo32);
                if (hi32) atomicOr(&rowbits[base + 1], hi32);
            }
        }
    }
    __syncthreads();

    // Apply to all 3 channels at this (h,w4) position.
    int p  = posF0 + t;                 // position within channel [0, CHAN4)
    int w4 = p % W4;
    int h  = p / W4;
    unsigned int word = rowbits[(h - h0) * 7 + (w4 >> 3)];
    unsigned int m4 = (word >> ((w4 & 7) * 4)) & 0xFu;

    size_t f0 = (size_t)b * PER_IMG4 + p;            // channel 0
    vfloat4 z = {0.f, 0.f, 0.f, 0.f};
    vfloat4 v0 = z, v1 = z, v2 = z;
    if (m4 != 0xFu) {                    // all 4 px masked: skip the loads
        v0 = __builtin_nontemporal_load(&imgs[f0]);
        v1 = __builtin_nontemporal_load(&imgs[f0 + CHAN4]);
        v2 = __builtin_nontemporal_load(&imgs[f0 + 2 * CHAN4]);
        if (m4 & 1u) { v0.x = 0.f; v1.x = 0.f; v2.x = 0.f; }
        if (m4 & 2u) { v0.y = 0.f; v1.y = 0.f; v2.y = 0.f; }
        if (m4 & 4u) { v0.z = 0.f; v1.z = 0.f; v2.z = 0.f; }
        if (m4 & 8u) { v0.w = 0.f; v1.w = 0.f; v2.w = 0.f; }
    }
    __builtin_nontemporal_store(v0, &out[f0]);
    __builtin_nontemporal_store(v1, &out[f0 + CHAN4]);
    __builtin_nontemporal_store(v2, &out[f0 + 2 * CHAN4]);
}

extern "C" void kernel_launch(void* const* d_in, const int* in_sizes, int n_in,
                              void* d_out, int out_size, void* d_ws, size_t ws_size,
                              hipStream_t stream) {
    const float* imgs = (const float*)d_in[0];
    const int*   px   = (const int*)d_in[1];
    const int*   py   = (const int*)d_in[2];
    float*       out  = (float*)d_out;

    const int N = in_sizes[1] / BB;  // points per image (98)

    occl_fused<<<NBLK, 256, 0, stream>>>(
        (vfloat4*)out, (const vfloat4*)imgs, px, py, N);
}